// Round 2
// baseline (1204.703 us; speedup 1.0000x reference)
//
#include <hip/hip_runtime.h>
#include <math.h>

#define SEQ 4096
#define DM  1024

#define BM 128
#define BN 128
#define BK 16
#define PAD 4
#define NCT (SEQ / BN)   // 32 column tiles

union U4 { uint4 u; unsigned short s[8]; };

__device__ __forceinline__ float bf2f(unsigned short u) {
    return __uint_as_float(((unsigned int)u) << 16);
}
__device__ __forceinline__ unsigned short f2bf(float f) {
    unsigned int u = __float_as_uint(f);
    return (unsigned short)((u + 0x7FFFu + ((u >> 16) & 1u)) >> 16);
}

// Decide whether buffer holds packed bf16 (1) or fp32 (0).
// bf16 N(0,1): bits14:7 of each u32 = exponent in [112,140] nearly always.
// fp32 N(0,1): bits14:7 are mantissa bits, ~uniform -> ~11% hit rate.
__device__ __forceinline__ int detect_bf16(const void* p0) {
    const unsigned int* p = (const unsigned int*)p0;
    int cnt = 0;
    #pragma unroll
    for (int i = 0; i < 64; i++) {
        unsigned int e = (p[i] >> 7) & 0xFFu;
        cnt += (e >= 112u && e <= 140u) ? 1 : 0;
    }
    return cnt >= 48 ? 1 : 0;
}

// load 8 consecutive elements (element index idx, multiple of 8) as fp32
__device__ __forceinline__ void load8(const void* base, size_t idx, int isbf, float* v) {
    if (isbf) {
        U4 t; t.u = *(const uint4*)((const unsigned short*)base + idx);
        #pragma unroll
        for (int q = 0; q < 8; q++) v[q] = bf2f(t.s[q]);
    } else {
        const float* f = (const float*)base + idx;
        float4 a = *(const float4*)f;
        float4 b = *(const float4*)(f + 4);
        v[0] = a.x; v[1] = a.y; v[2] = a.z; v[3] = a.w;
        v[4] = b.x; v[5] = b.y; v[6] = b.z; v[7] = b.w;
    }
}

// ---------------- kernel 1: Q = (x @ wq) * scale   (NN GEMM, flagged inputs)
__global__ __launch_bounds__(256)
void proj_q_kernel(const void* __restrict__ X, const void* __restrict__ W,
                   float* __restrict__ C, float scale)
{
    __shared__ float As[BK][BM + PAD];
    __shared__ float Bs[BK][BN + PAD];
    const int isbf = detect_bf16(X);
    const int t  = threadIdx.x;
    const int bx = blockIdx.x;   // n tile (over DM)
    const int by = blockIdx.y;   // m tile (over SEQ)
    const int tm = t >> 4, tn = t & 15;

    float acc[8][8];
    #pragma unroll
    for (int i = 0; i < 8; i++)
        #pragma unroll
        for (int j = 0; j < 8; j++) acc[i][j] = 0.f;

    const int ar = t >> 1;           // 0..127 row within tile
    const int ak = (t & 1) * 8;      // 0/8
    const int wr = t >> 4;           // 0..15 k row
    const int wn = (t & 15) * 8;     // col offset

    for (int kt = 0; kt < DM; kt += BK) {
        float av[8], wv[8];
        load8(X, (size_t)(by * BM + ar) * DM + kt + ak, isbf, av);
        load8(W, (size_t)(kt + wr) * DM + bx * BN + wn, isbf, wv);
        #pragma unroll
        for (int q = 0; q < 8; q++) As[ak + q][ar] = av[q];
        #pragma unroll
        for (int q = 0; q < 8; q++) Bs[wr][wn + q] = wv[q];
        __syncthreads();
        #pragma unroll
        for (int kk = 0; kk < BK; kk++) {
            float a[8], b[8];
            #pragma unroll
            for (int i = 0; i < 8; i++) a[i] = As[kk][tm * 8 + i];
            #pragma unroll
            for (int j = 0; j < 8; j++) b[j] = Bs[kk][tn * 8 + j];
            #pragma unroll
            for (int i = 0; i < 8; i++)
                #pragma unroll
                for (int j = 0; j < 8; j++)
                    acc[i][j] = fmaf(a[i], b[j], acc[i][j]);
        }
        __syncthreads();
    }
    #pragma unroll
    for (int i = 0; i < 8; i++) {
        float* cp = C + (size_t)(by * BM + tm * 8 + i) * DM + bx * BN + tn * 8;
        #pragma unroll
        for (int j = 0; j < 8; j++) cp[j] = acc[i][j] * scale;
    }
}

// ---------------- kernel 2: QW = Q @ wk^T-ish: QW[i,k] = sum_d Q[i,d]*wk[k,d]
// NT GEMM: A = Q (fp32), B = wk (flagged, rows indexed by n)
__global__ __launch_bounds__(256)
void proj_qw_kernel(const float* __restrict__ Q, const void* __restrict__ Wk,
                    float* __restrict__ QW)
{
    __shared__ float As[BK][BM + PAD];
    __shared__ float Bs[BK][BN + PAD];
    const int isbf = detect_bf16(Wk);
    const int t  = threadIdx.x;
    const int bx = blockIdx.x;   // n tile (over DM)
    const int by = blockIdx.y;   // m tile (over SEQ)
    const int tm = t >> 4, tn = t & 15;

    float acc[8][8];
    #pragma unroll
    for (int i = 0; i < 8; i++)
        #pragma unroll
        for (int j = 0; j < 8; j++) acc[i][j] = 0.f;

    const int ar = t >> 1;        // 0..127
    const int ak = (t & 1) * 8;   // 0/8

    for (int kt = 0; kt < DM; kt += BK) {
        const float* ap = Q + (size_t)(by * BM + ar) * DM + kt + ak;
        float4 a0 = *(const float4*)ap;
        float4 a1 = *(const float4*)(ap + 4);
        As[ak + 0][ar] = a0.x; As[ak + 1][ar] = a0.y; As[ak + 2][ar] = a0.z; As[ak + 3][ar] = a0.w;
        As[ak + 4][ar] = a1.x; As[ak + 5][ar] = a1.y; As[ak + 6][ar] = a1.z; As[ak + 7][ar] = a1.w;
        float bv[8];
        load8(Wk, (size_t)(bx * BN + ar) * DM + kt + ak, isbf, bv);
        #pragma unroll
        for (int q = 0; q < 8; q++) Bs[ak + q][ar] = bv[q];
        __syncthreads();
        #pragma unroll
        for (int kk = 0; kk < BK; kk++) {
            float a[8], b[8];
            #pragma unroll
            for (int i = 0; i < 8; i++) a[i] = As[kk][tm * 8 + i];
            #pragma unroll
            for (int j = 0; j < 8; j++) b[j] = Bs[kk][tn * 8 + j];
            #pragma unroll
            for (int i = 0; i < 8; i++)
                #pragma unroll
                for (int j = 0; j < 8; j++)
                    acc[i][j] = fmaf(a[i], b[j], acc[i][j]);
        }
        __syncthreads();
    }
    #pragma unroll
    for (int i = 0; i < 8; i++) {
        float* cp = QW + (size_t)(by * BM + tm * 8 + i) * DM + bx * BN + tn * 8;
        #pragma unroll
        for (int j = 0; j < 8; j++) cp[j] = acc[i][j];
    }
}

// ---------------- scores: S[i,j] = sum_k QW[i,k] * x[j,k]   (NT, B = x flagged)
// PASS 1: per-(coltile,row) max/sumexp partials. PASS 2: normalized bf16/fp32 out.
template <int PASS>
__global__ __launch_bounds__(256)
void scores_kernel(const float* __restrict__ QW, const void* __restrict__ X,
                   float* __restrict__ pm, float* __restrict__ pl,
                   const float* __restrict__ row_m, const float* __restrict__ row_il,
                   void* __restrict__ out)
{
    __shared__ float As[BK][BM + PAD];
    __shared__ float Bs[BK][BN + PAD];
    __shared__ float red[BM][17];
    __shared__ float rowred[BM];

    const int isbf = detect_bf16(X);
    const int t  = threadIdx.x;
    const int bx = blockIdx.x;   // col tile
    const int by = blockIdx.y;   // row tile
    const int tm = t >> 4, tn = t & 15;

    float acc[8][8];
    #pragma unroll
    for (int i = 0; i < 8; i++)
        #pragma unroll
        for (int j = 0; j < 8; j++) acc[i][j] = 0.f;

    const int ar = t >> 1;
    const int ak = (t & 1) * 8;

    for (int kt = 0; kt < DM; kt += BK) {
        const float* ap = QW + (size_t)(by * BM + ar) * DM + kt + ak;
        float4 a0 = *(const float4*)ap;
        float4 a1 = *(const float4*)(ap + 4);
        As[ak + 0][ar] = a0.x; As[ak + 1][ar] = a0.y; As[ak + 2][ar] = a0.z; As[ak + 3][ar] = a0.w;
        As[ak + 4][ar] = a1.x; As[ak + 5][ar] = a1.y; As[ak + 6][ar] = a1.z; As[ak + 7][ar] = a1.w;
        float bv[8];
        load8(X, (size_t)(bx * BN + ar) * DM + kt + ak, isbf, bv);
        #pragma unroll
        for (int q = 0; q < 8; q++) Bs[ak + q][ar] = bv[q];
        __syncthreads();
        #pragma unroll
        for (int kk = 0; kk < BK; kk++) {
            float a[8], b[8];
            #pragma unroll
            for (int i = 0; i < 8; i++) a[i] = As[kk][tm * 8 + i];
            #pragma unroll
            for (int j = 0; j < 8; j++) b[j] = Bs[kk][tn * 8 + j];
            #pragma unroll
            for (int i = 0; i < 8; i++)
                #pragma unroll
                for (int j = 0; j < 8; j++)
                    acc[i][j] = fmaf(a[i], b[j], acc[i][j]);
        }
        __syncthreads();
    }

    if (PASS == 1) {
        #pragma unroll
        for (int i = 0; i < 8; i++) {
            float m = acc[i][0];
            #pragma unroll
            for (int j = 1; j < 8; j++) m = fmaxf(m, acc[i][j]);
            red[tm * 8 + i][tn] = m;
        }
        __syncthreads();
        if (t < BM) {
            float m = red[t][0];
            #pragma unroll
            for (int q = 1; q < 16; q++) m = fmaxf(m, red[t][q]);
            rowred[t] = m;
        }
        __syncthreads();
        #pragma unroll
        for (int i = 0; i < 8; i++) {
            float m = rowred[tm * 8 + i];
            float s = 0.f;
            #pragma unroll
            for (int j = 0; j < 8; j++) s += __expf(acc[i][j] - m);
            red[tm * 8 + i][tn] = s;
        }
        __syncthreads();
        if (t < BM) {
            float s = 0.f;
            #pragma unroll
            for (int q = 0; q < 16; q++) s += red[t][q];
            int grow = by * BM + t;
            pm[(size_t)bx * SEQ + grow] = rowred[t];
            pl[(size_t)bx * SEQ + grow] = s;
        }
    } else {
        #pragma unroll
        for (int i = 0; i < 8; i++) {
            int row = by * BM + tm * 8 + i;
            float m  = row_m[row];
            float il = row_il[row];
            if (isbf) {
                U4 o;
                #pragma unroll
                for (int j = 0; j < 8; j++)
                    o.s[j] = f2bf(__expf(acc[i][j] - m) * il);
                *(uint4*)((unsigned short*)out + (size_t)row * SEQ + bx * BN + tn * 8) = o.u;
            } else {
                float* op = (float*)out + (size_t)row * SEQ + bx * BN + tn * 8;
                float4 o0, o1;
                o0.x = __expf(acc[i][0] - m) * il; o0.y = __expf(acc[i][1] - m) * il;
                o0.z = __expf(acc[i][2] - m) * il; o0.w = __expf(acc[i][3] - m) * il;
                o1.x = __expf(acc[i][4] - m) * il; o1.y = __expf(acc[i][5] - m) * il;
                o1.z = __expf(acc[i][6] - m) * il; o1.w = __expf(acc[i][7] - m) * il;
                *(float4*)op = o0;
                *(float4*)(op + 4) = o1;
            }
        }
    }
}

__global__ __launch_bounds__(256)
void reduce_kernel(const float* __restrict__ pm, const float* __restrict__ pl,
                   float* __restrict__ row_m, float* __restrict__ row_il)
{
    int r = blockIdx.x * 256 + threadIdx.x;
    if (r >= SEQ) return;
    float m = pm[r];
    #pragma unroll
    for (int ti = 1; ti < NCT; ti++) m = fmaxf(m, pm[(size_t)ti * SEQ + r]);
    float l = 0.f;
    #pragma unroll
    for (int ti = 0; ti < NCT; ti++)
        l += pl[(size_t)ti * SEQ + r] * __expf(pm[(size_t)ti * SEQ + r] - m);
    row_m[r]  = m;
    row_il[r] = 1.f / l;
}

extern "C" void kernel_launch(void* const* d_in, const int* in_sizes, int n_in,
                              void* d_out, int out_size, void* d_ws, size_t ws_size,
                              hipStream_t stream)
{
    const void* x  = d_in[0];
    const void* wq = d_in[1];
    const void* wk = d_in[2];
    // d_in[3] (w_v), d_in[4] (out_proj) unused by the reference output.

    // ws layout: total EXACTLY 32 MiB.
    // [0,16MB):  QW  (lives until the end)
    // [16,32MB): Q   (dead after proj_qw) -> overlaid by pm/pl/rm/ril
    float* QW = (float*)d_ws;
    float* Q  = QW + (size_t)SEQ * DM;
    float* pm  = Q;                        // 32*4096 floats = 512 KB
    float* pl  = pm + (size_t)NCT * SEQ;   // 512 KB
    float* rm  = pl + (size_t)NCT * SEQ;   // 16 KB
    float* ril = rm + SEQ;                 // 16 KB

    dim3 blk(256);
    // Q scaled by 1/sqrt(1024) = 2^-5 (exact power of two)
    proj_q_kernel <<<dim3(DM / BN, SEQ / BM), blk, 0, stream>>>(x, wq, Q, 0.03125f);
    proj_qw_kernel<<<dim3(DM / BN, SEQ / BM), blk, 0, stream>>>(Q, wk, QW);
    scores_kernel<1><<<dim3(SEQ / BN, SEQ / BM), blk, 0, stream>>>(QW, x, pm, pl, nullptr, nullptr, nullptr);
    reduce_kernel<<<dim3(SEQ / 256), blk, 0, stream>>>(pm, pl, rm, ril);
    scores_kernel<2><<<dim3(SEQ / BN, SEQ / BM), blk, 0, stream>>>(QW, x, nullptr, nullptr, rm, ril, d_out);
}

// Round 7
// 1189.877 us; speedup vs baseline: 1.0125x; 1.0125x over previous
//
#include <hip/hip_runtime.h>
#include <math.h>

#define SEQ 4096
#define DM  1024

#define BM 128
#define BN 128
#define BK 16
#define PAD 4
#define NCT (SEQ / BN)   // 32 column tiles

union U4 { uint4 u; unsigned short s[8]; };

__device__ __forceinline__ float bf2f(unsigned short u) {
    return __uint_as_float(((unsigned int)u) << 16);
}
__device__ __forceinline__ unsigned short f2bf(float f) {
    unsigned int u = __float_as_uint(f);
    return (unsigned short)((u + 0x7FFFu + ((u >> 16) & 1u)) >> 16);
}

// Decide whether buffer holds packed bf16 (1) or fp32 (0).
__device__ __forceinline__ int detect_bf16(const void* p0) {
    const unsigned int* p = (const unsigned int*)p0;
    int cnt = 0;
    #pragma unroll
    for (int i = 0; i < 64; i++) {
        unsigned int e = (p[i] >> 7) & 0xFFu;
        cnt += (e >= 112u && e <= 140u) ? 1 : 0;
    }
    return cnt >= 48 ? 1 : 0;
}

// load 8 consecutive elements (element index idx, multiple of 8) as fp32
__device__ __forceinline__ void load8(const void* base, size_t idx, int isbf, float* v) {
    if (isbf) {
        U4 t; t.u = *(const uint4*)((const unsigned short*)base + idx);
        #pragma unroll
        for (int q = 0; q < 8; q++) v[q] = bf2f(t.s[q]);
    } else {
        const float* f = (const float*)base + idx;
        float4 a = *(const float4*)f;
        float4 b = *(const float4*)(f + 4);
        v[0] = a.x; v[1] = a.y; v[2] = a.z; v[3] = a.w;
        v[4] = b.x; v[5] = b.y; v[6] = b.z; v[7] = b.w;
    }
}

// ---------------- kernel 1: Q = (x @ wq) * scale   (NN GEMM, flagged inputs)
__global__ __launch_bounds__(256)
void proj_q_kernel(const void* __restrict__ X, const void* __restrict__ W,
                   float* __restrict__ C, float scale)
{
    __shared__ float As[BK][BM + PAD];
    __shared__ float Bs[BK][BN + PAD];
    const int isbf = detect_bf16(X);
    const int t  = threadIdx.x;
    const int bx = blockIdx.x;   // n tile (over DM)
    const int by = blockIdx.y;   // m tile (over SEQ)
    const int tm = t >> 4, tn = t & 15;

    float acc[8][8];
    #pragma unroll
    for (int i = 0; i < 8; i++)
        #pragma unroll
        for (int j = 0; j < 8; j++) acc[i][j] = 0.f;

    const int ar = t >> 1;           // 0..127 row within tile
    const int ak = (t & 1) * 8;      // 0/8
    const int wr = t >> 4;           // 0..15 k row
    const int wn = (t & 15) * 8;     // col offset

    for (int kt = 0; kt < DM; kt += BK) {
        float av[8], wv[8];
        load8(X, (size_t)(by * BM + ar) * DM + kt + ak, isbf, av);
        load8(W, (size_t)(kt + wr) * DM + bx * BN + wn, isbf, wv);
        #pragma unroll
        for (int q = 0; q < 8; q++) As[ak + q][ar] = av[q];
        #pragma unroll
        for (int q = 0; q < 8; q++) Bs[wr][wn + q] = wv[q];
        __syncthreads();
        #pragma unroll
        for (int kk = 0; kk < BK; kk++) {
            float a[8], b[8];
            #pragma unroll
            for (int i = 0; i < 8; i++) a[i] = As[kk][tm * 8 + i];
            #pragma unroll
            for (int j = 0; j < 8; j++) b[j] = Bs[kk][tn * 8 + j];
            #pragma unroll
            for (int i = 0; i < 8; i++)
                #pragma unroll
                for (int j = 0; j < 8; j++)
                    acc[i][j] = fmaf(a[i], b[j], acc[i][j]);
        }
        __syncthreads();
    }
    #pragma unroll
    for (int i = 0; i < 8; i++) {
        float* cp = C + (size_t)(by * BM + tm * 8 + i) * DM + bx * BN + tn * 8;
        #pragma unroll
        for (int j = 0; j < 8; j++) cp[j] = acc[i][j] * scale;
    }
}

// ---------------- kernel 2: QW[i,n] = sum_d Q[i,d] * wk[n,d]   (NT, A fp32, B flagged)
__global__ __launch_bounds__(256)
void proj_qw_kernel(const float* __restrict__ Q, const void* __restrict__ Wk,
                    float* __restrict__ QW)
{
    __shared__ float As[BK][BM + PAD];
    __shared__ float Bs[BK][BN + PAD];
    const int isbf = detect_bf16(Wk);
    const int t  = threadIdx.x;
    const int bx = blockIdx.x;   // n tile (over DM)
    const int by = blockIdx.y;   // m tile (over SEQ)
    const int tm = t >> 4, tn = t & 15;

    float acc[8][8];
    #pragma unroll
    for (int i = 0; i < 8; i++)
        #pragma unroll
        for (int j = 0; j < 8; j++) acc[i][j] = 0.f;

    const int ar = t >> 1;        // 0..127
    const int ak = (t & 1) * 8;   // 0/8

    for (int kt = 0; kt < DM; kt += BK) {
        const float* ap = Q + (size_t)(by * BM + ar) * DM + kt + ak;
        float4 a0 = *(const float4*)ap;
        float4 a1 = *(const float4*)(ap + 4);
        As[ak + 0][ar] = a0.x; As[ak + 1][ar] = a0.y; As[ak + 2][ar] = a0.z; As[ak + 3][ar] = a0.w;
        As[ak + 4][ar] = a1.x; As[ak + 5][ar] = a1.y; As[ak + 6][ar] = a1.z; As[ak + 7][ar] = a1.w;
        float bv[8];
        load8(Wk, (size_t)(bx * BN + ar) * DM + kt + ak, isbf, bv);
        #pragma unroll
        for (int q = 0; q < 8; q++) Bs[ak + q][ar] = bv[q];
        __syncthreads();
        #pragma unroll
        for (int kk = 0; kk < BK; kk++) {
            float a[8], b[8];
            #pragma unroll
            for (int i = 0; i < 8; i++) a[i] = As[kk][tm * 8 + i];
            #pragma unroll
            for (int j = 0; j < 8; j++) b[j] = Bs[kk][tn * 8 + j];
            #pragma unroll
            for (int i = 0; i < 8; i++)
                #pragma unroll
                for (int j = 0; j < 8; j++)
                    acc[i][j] = fmaf(a[i], b[j], acc[i][j]);
        }
        __syncthreads();
    }
    #pragma unroll
    for (int i = 0; i < 8; i++) {
        float* cp = QW + (size_t)(by * BM + tm * 8 + i) * DM + bx * BN + tn * 8;
        #pragma unroll
        for (int j = 0; j < 8; j++) cp[j] = acc[i][j];
    }
}

// ---------------- scores: S[i,j] = sum_k QW[i,k] * x[j,k]   (NT, B = x flagged)
// PASS 1: per-(coltile,row) max and sumexp partials. PASS 2: normalized output.
template <int PASS>
__global__ __launch_bounds__(256)
void scores_kernel(const float* __restrict__ QW, const void* __restrict__ X,
                   float* __restrict__ pm, float* __restrict__ pl,
                   const float* __restrict__ row_m, const float* __restrict__ row_il,
                   void* __restrict__ out)
{
    __shared__ float As[BK][BM + PAD];
    __shared__ float Bs[BK][BN + PAD];
    __shared__ float red[BM][17];
    __shared__ float rowred[BM];

    const int isbf = detect_bf16(X);
    const int t  = threadIdx.x;
    const int bx = blockIdx.x;   // col tile
    const int by = blockIdx.y;   // row tile
    const int tm = t >> 4, tn = t & 15;

    float acc[8][8];
    #pragma unroll
    for (int i = 0; i < 8; i++)
        #pragma unroll
        for (int j = 0; j < 8; j++) acc[i][j] = 0.f;

    const int ar = t >> 1;
    const int ak = (t & 1) * 8;

    for (int kt = 0; kt < DM; kt += BK) {
        const float* ap = QW + (size_t)(by * BM + ar) * DM + kt + ak;
        float4 a0 = *(const float4*)ap;
        float4 a1 = *(const float4*)(ap + 4);
        As[ak + 0][ar] = a0.x; As[ak + 1][ar] = a0.y; As[ak + 2][ar] = a0.z; As[ak + 3][ar] = a0.w;
        As[ak + 4][ar] = a1.x; As[ak + 5][ar] = a1.y; As[ak + 6][ar] = a1.z; As[ak + 7][ar] = a1.w;
        float bv[8];
        load8(X, (size_t)(bx * BN + ar) * DM + kt + ak, isbf, bv);
        #pragma unroll
        for (int q = 0; q < 8; q++) Bs[ak + q][ar] = bv[q];
        __syncthreads();
        #pragma unroll
        for (int kk = 0; kk < BK; kk++) {
            float a[8], b[8];
            #pragma unroll
            for (int i = 0; i < 8; i++) a[i] = As[kk][tm * 8 + i];
            #pragma unroll
            for (int j = 0; j < 8; j++) b[j] = Bs[kk][tn * 8 + j];
            #pragma unroll
            for (int i = 0; i < 8; i++)
                #pragma unroll
                for (int j = 0; j < 8; j++)
                    acc[i][j] = fmaf(a[i], b[j], acc[i][j]);
        }
        __syncthreads();
    }

    if (PASS == 1) {
        #pragma unroll
        for (int i = 0; i < 8; i++) {
            float m = acc[i][0];
            #pragma unroll
            for (int j = 1; j < 8; j++) m = fmaxf(m, acc[i][j]);
            red[tm * 8 + i][tn] = m;
        }
        __syncthreads();
        if (t < BM) {
            float m = red[t][0];
            #pragma unroll
            for (int q = 1; q < 16; q++) m = fmaxf(m, red[t][q]);
            rowred[t] = m;
        }
        __syncthreads();
        #pragma unroll
        for (int i = 0; i < 8; i++) {
            float m = rowred[tm * 8 + i];
            float s = 0.f;
            #pragma unroll
            for (int j = 0; j < 8; j++) s += __expf(acc[i][j] - m);
            red[tm * 8 + i][tn] = s;
        }
        __syncthreads();
        if (t < BM) {
            float s = 0.f;
            #pragma unroll
            for (int q = 0; q < 16; q++) s += red[t][q];
            int grow = by * BM + t;
            pm[(size_t)bx * SEQ + grow] = rowred[t];
            pl[(size_t)bx * SEQ + grow] = s;
        }
    } else {
        #pragma unroll
        for (int i = 0; i < 8; i++) {
            int row = by * BM + tm * 8 + i;
            float m  = row_m[row];
            float il = row_il[row];
            if (isbf) {
                U4 o;
                #pragma unroll
                for (int j = 0; j < 8; j++)
                    o.s[j] = f2bf(__expf(acc[i][j] - m) * il);
                *(uint4*)((unsigned short*)out + (size_t)row * SEQ + bx * BN + tn * 8) = o.u;
            } else {
                float* op = (float*)out + (size_t)row * SEQ + bx * BN + tn * 8;
                float4 o0, o1;
                o0.x = __expf(acc[i][0] - m) * il; o0.y = __expf(acc[i][1] - m) * il;
                o0.z = __expf(acc[i][2] - m) * il; o0.w = __expf(acc[i][3] - m) * il;
                o1.x = __expf(acc[i][4] - m) * il; o1.y = __expf(acc[i][5] - m) * il;
                o1.z = __expf(acc[i][6] - m) * il; o1.w = __expf(acc[i][7] - m) * il;
                *(float4*)op = o0;
                *(float4*)(op + 4) = o1;
            }
        }
    }
}

__global__ __launch_bounds__(256)
void reduce_kernel(const float* __restrict__ pm, const float* __restrict__ pl,
                   float* __restrict__ row_m, float* __restrict__ row_il)
{
    int r = blockIdx.x * 256 + threadIdx.x;
    if (r >= SEQ) return;
    float m = pm[r];
    #pragma unroll
    for (int ti = 1; ti < NCT; ti++) m = fmaxf(m, pm[(size_t)ti * SEQ + r]);
    float l = 0.f;
    #pragma unroll
    for (int ti = 0; ti < NCT; ti++)
        l += pl[(size_t)ti * SEQ + r] * __expf(pm[(size_t)ti * SEQ + r] - m);
    row_m[r]  = m;
    row_il[r] = 1.f / l;
}

extern "C" void kernel_launch(void* const* d_in, const int* in_sizes, int n_in,
                              void* d_out, int out_size, void* d_ws, size_t ws_size,
                              hipStream_t stream)
{
    const void* x  = d_in[0];
    const void* wq = d_in[1];
    const void* wk = d_in[2];
    // d_in[3] (w_v), d_in[4] (out_proj) unused by the reference output.

    // NO-ALIAS layout (the overlay of partials onto dead Q is the prime
    // suspect for the nondeterministic NaNs — eliminated entirely):
    //   ws[0,16MB):       QW fp32 (live until the end)
    //   ws[16MB,17.1MB):  pm / pl / rm / ril (fresh, never-aliased space)
    //   d_out[0,16MB):    Q fp32 scratch — dead before scores<2> writes d_out
    float* QW  = (float*)d_ws;
    float* pm  = QW + (size_t)SEQ * DM;        // 32*4096 floats
    float* pl  = pm + (size_t)NCT * SEQ;       // 32*4096 floats
    float* rm  = pl + (size_t)NCT * SEQ;       // 4096 floats
    float* ril = rm + SEQ;                     // 4096 floats  (total ~17.06 MB <= 32 MiB)
    float* Q   = (float*)d_out;                // scratch in output buffer

    dim3 blk(256);
    // Q scaled by 1/sqrt(1024) = 2^-5 (exact)
    proj_q_kernel <<<dim3(DM / BN, SEQ / BM), blk, 0, stream>>>(x, wq, Q, 0.03125f);
    proj_qw_kernel<<<dim3(DM / BN, SEQ / BM), blk, 0, stream>>>(Q, wk, QW);
    scores_kernel<1><<<dim3(SEQ / BN, SEQ / BM), blk, 0, stream>>>(QW, x, pm, pl, nullptr, nullptr, nullptr);
    reduce_kernel <<<dim3(SEQ / 256), blk, 0, stream>>>(pm, pl, rm, ril);
    scores_kernel<2><<<dim3(SEQ / BN, SEQ / BM), blk, 0, stream>>>(QW, x, nullptr, nullptr, rm, ril, d_out);
}